// Round 2
// baseline (263.916 us; speedup 1.0000x reference)
//
#include <hip/hip_runtime.h>

// SpatialAttention fp32: B=128, C=3, H=W=256, 8x8 patches, FEAT=192, ENC=16.
// 131072 independent patches, one per lane. No LDS, no barriers.
// enc = relu(Wenc.xp + benc); out = relu(Wdec.enc + bdec);
// y = softmax(out)*out. out >= 0 and bounded (~<=12), so softmax needs no
// max-subtraction; decoder is recomputed in pass 2 instead of storing out[192].
// Memory-bound: 200 MB @ 6.3 TB/s => ~32 us floor. VALU ~9.2K fma/patch ~15 us.

constexpr int NPATCH = 128 * 32 * 32;
constexpr float L2E = 1.4426950408889634f;

__global__ __launch_bounds__(256) void spatial_attn(
    const float* __restrict__ x,      // [128][3][256][256]
    const float* __restrict__ Wenc,   // [16][192]
    const float* __restrict__ benc,   // [16]
    const float* __restrict__ Wdec,   // [192][16]
    const float* __restrict__ bdec,   // [192]
    float* __restrict__ y)            // [128][3][256][256]
{
  const int p  = blockIdx.x * 256 + threadIdx.x;   // one patch per lane
  const int b  = p >> 10;
  const int ii = (p >> 5) & 31;
  const int jj = p & 31;
  // element offset of (c,r) row-slice: base + c*65536 + r*256
  const size_t base = (size_t)b * 196608 + (size_t)ii * 2048 + (size_t)jj * 8;

  // ---- Encoder, streaming: acc[e] = benc[e] + sum_f Wenc[e][f]*xp[f] ----
  float acc[16];
  #pragma unroll
  for (int e = 0; e < 16; ++e) acc[e] = benc[e];   // wave-uniform scalar loads

  #pragma unroll 4
  for (int cr = 0; cr < 24; ++cr) {                // 24 slices of 8 floats
    const float* src = x + base + (cr >> 3) * 65536 + (cr & 7) * 256;
    const float4 v0 = *(const float4*)(src);
    const float4 v1 = *(const float4*)(src + 4);
    const float xv[8] = {v0.x, v0.y, v0.z, v0.w, v1.x, v1.y, v1.z, v1.w};
    #pragma unroll
    for (int e = 0; e < 16; ++e) {
      const float* w = Wenc + e * 192 + cr * 8;    // wave-uniform -> s_load
      #pragma unroll
      for (int q = 0; q < 8; ++q) acc[e] = fmaf(w[q], xv[q], acc[e]);
    }
  }
  #pragma unroll
  for (int e = 0; e < 16; ++e) acc[e] = fmaxf(acc[e], 0.0f);

  // ---- Pass 1: softmax denominator over the 192 decoder outputs ----
  float s = 0.0f;
  #pragma unroll 4
  for (int f = 0; f < 192; ++f) {
    const float* w = Wdec + f * 16;                // wave-uniform -> s_load
    float o = bdec[f];
    #pragma unroll
    for (int e = 0; e < 16; ++e) o = fmaf(w[e], acc[e], o);
    o = fmaxf(o, 0.0f);
    s += __builtin_amdgcn_exp2f(o * L2E);
  }
  const float inv = __builtin_amdgcn_rcpf(s);

  // ---- Pass 2: recompute out, y = exp(out)/s * out, coalesced stores ----
  #pragma unroll 1
  for (int cr = 0; cr < 24; ++cr) {
    float o8[8];
    #pragma unroll
    for (int q = 0; q < 8; ++q) {
      const int f = cr * 8 + q;
      const float* w = Wdec + f * 16;
      float o = bdec[f];
      #pragma unroll
      for (int e = 0; e < 16; ++e) o = fmaf(w[e], acc[e], o);
      o = fmaxf(o, 0.0f);
      o8[q] = __builtin_amdgcn_exp2f(o * L2E) * inv * o;
    }
    float* dst = y + base + (cr >> 3) * 65536 + (cr & 7) * 256;
    const float4 s0 = {o8[0], o8[1], o8[2], o8[3]};
    const float4 s1 = {o8[4], o8[5], o8[6], o8[7]};
    *(float4*)(dst)     = s0;
    *(float4*)(dst + 4) = s1;
  }
}

extern "C" void kernel_launch(void* const* d_in, const int* in_sizes, int n_in,
                              void* d_out, int out_size, void* d_ws, size_t ws_size,
                              hipStream_t stream) {
  const float* x    = (const float*)d_in[0];
  const float* Wenc = (const float*)d_in[1];
  const float* benc = (const float*)d_in[2];
  const float* Wdec = (const float*)d_in[3];
  const float* bdec = (const float*)d_in[4];
  float* y = (float*)d_out;
  dim3 grid(NPATCH / 256), block(256);
  hipLaunchKernelGGL(spatial_attn, grid, block, 0, stream, x, Wenc, benc, Wdec, bdec, y);
}